// Round 6
// baseline (306.967 us; speedup 1.0000x reference)
//
#include <hip/hip_runtime.h>
#include <cstdint>
#include <cstddef>

#define B_ 16
#define S_ 2048
#define D_ 128
#define M_ 32            // q-rows per block
#define NW 8             // waves per block
#define KPW 256          // keys per wave
#define OST 136          // opart row stride in halves (16B-aligned rows)

typedef float  f32x4 __attribute__((ext_vector_type(4)));
typedef _Float16 f16x8 __attribute__((ext_vector_type(8)));
typedef _Float16 f16x4 __attribute__((ext_vector_type(4)));

// log2(e) / sqrt(128)
#define SCALE_ 0.12751743f

#define NE_ ((size_t)B_ * S_ * D_)   // 4,194,304 per tensor

// ---------------- pre-pass ----------------
// blocks [0,2048): V -> Vt2, PV-fragment-native tiled layout:
//   Vt2[((b*128 + kt)*8 + dt)*64 + lane][i]  (f16, i=0..3)
//   holds V[b][key = kt*16 + 4*(lane>>4) + i][d = dt*16 + (lane&15)]
//   -> the 16x16x16 PV B-frag load is ONE contiguous 512B wave read.
// blocks [2048,3072): K f32 -> f16 row-major
__global__ void prepass_kernel(const float* __restrict__ K,
                               const float* __restrict__ V,
                               _Float16* __restrict__ Kh,
                               _Float16* __restrict__ Vt2) {
  const int blk = blockIdx.x;
  if (blk < 2048) {
    const int b  = blk >> 7;        // 16 batches
    const int kt = blk & 127;       // 128 key-tiles of 16
    const int tid = threadIdx.x;
    const int lg = tid >> 6;        // 0..3
    const int i  = (tid >> 4) & 3;  // 0..3
    const int lr = tid & 15;        // 0..15
    const size_t vrow = ((size_t)b * S_ + kt * 16 + 4 * lg + i) * D_;
    const size_t obase = (((size_t)(b * 128 + kt) * 8) * 64 + lg * 16 + lr) * 4 + i;
#pragma unroll
    for (int dt = 0; dt < 8; ++dt) {
      float val = V[vrow + dt * 16 + lr];
      Vt2[obase + (size_t)dt * 256] = (_Float16)val;   // dt stride = 64*4 halves
    }
  } else {
    int rel = blk - 2048;      // 0..1023
    const int n4 = (int)(NE_ / 4);
    for (int i = rel * 256 + (int)threadIdx.x; i < n4; i += 1024 * 256) {
      f32x4 v = ((const f32x4*)K)[i];
      f16x4 h;
      for (int j = 0; j < 4; ++j) h[j] = (_Float16)v[j];
      ((f16x4*)Kh)[i] = h;
    }
  }
}

// ---------------- fused attention, P fully in registers ----------------
// QK^T computed SWAPPED: S^T tile = mfma16x16x32(A=K rows, B=Q rows).
// Lane(lr,lg) holds S^T[key=16t+4lg+r][qrow=16h+lr]; after exp+f16-pack,
// pp[h][t] is exactly the A-frag of v_mfma_f32_16x16x16_f16. P never
// touches LDS. ONE barrier total; all global stores after it.
template <bool WS>
__global__ __launch_bounds__(512, 2)
void attn_fused(const float* __restrict__ Qf, const float* __restrict__ Kf,
                const float* __restrict__ Vf,
                const _Float16* __restrict__ Kh, const _Float16* __restrict__ Vt2,
                float* __restrict__ outO, float* __restrict__ outA) {
  __shared__ _Float16 opart[NW][M_][OST];   // per-wave O partials (~69.6 KB)
  __shared__ float wsum[NW][M_];

  const int tid  = threadIdx.x;
  const int w    = tid >> 6;
  const int lane = tid & 63;
  const int lg   = lane >> 4;   // 0..3
  const int lr   = lane & 15;   // 0..15
  const int blk  = blockIdx.x;
  const int b    = blk & 15;    // batch -> XCD = b&7 (2 batches per XCD L2)
  const int qt   = blk >> 4;    // 0..63
  const int q0   = qt * M_;
  const int key0 = w * KPW;

  // ---- Q B-frags: B[k=32kk+8lg+j][n=qrow=16h+lr] (load f32, cvt f16) ----
  f16x8 bq[2][4];
  for (int h = 0; h < 2; ++h) {
    const float* qp = Qf + ((size_t)b * S_ + q0 + 16 * h + lr) * D_;
    for (int kk = 0; kk < 4; ++kk) {
      const float* p = qp + kk * 32 + lg * 8;
      f32x4 v0 = *(const f32x4*)p, v1 = *(const f32x4*)(p + 4);
      f16x8 a;
      for (int j = 0; j < 4; ++j) { a[j] = (_Float16)v0[j]; a[4 + j] = (_Float16)v1[j]; }
      bq[h][kk] = a;
    }
  }

  // ---- Phase 1: S^T = K·Q^T, P = exp(S/temper) packed in registers ----
  f16x4 pp[2][16];            // 64 VGPRs: the PV A-fragments
  float psum[2] = {0.f, 0.f};
#pragma unroll 2
  for (int t = 0; t < 16; ++t) {
    f32x4 acc0 = {0.f, 0.f, 0.f, 0.f}, acc1 = {0.f, 0.f, 0.f, 0.f};
    const size_t krow = (size_t)b * S_ + key0 + 16 * t + lr;
    for (int kk = 0; kk < 4; ++kk) {
      // A[m=key row = lr][k = 32kk+8lg+j]
      f16x8 ka;
      if constexpr (WS) {
        ka = *(const f16x8*)(Kh + krow * D_ + kk * 32 + lg * 8);
      } else {
        const float* p = Kf + krow * D_ + kk * 32 + lg * 8;
        f32x4 v0 = *(const f32x4*)p, v1 = *(const f32x4*)(p + 4);
        for (int j = 0; j < 4; ++j) { ka[j] = (_Float16)v0[j]; ka[4 + j] = (_Float16)v1[j]; }
      }
      acc0 = __builtin_amdgcn_mfma_f32_16x16x32_f16(ka, bq[0][kk], acc0, 0, 0, 0);
      acc1 = __builtin_amdgcn_mfma_f32_16x16x32_f16(ka, bq[1][kk], acc1, 0, 0, 0);
    }
    f16x4 p0, p1;
    for (int r = 0; r < 4; ++r) {
      float e0 = __builtin_amdgcn_exp2f(acc0[r] * SCALE_);
      float e1 = __builtin_amdgcn_exp2f(acc1[r] * SCALE_);
      psum[0] += e0; psum[1] += e1;
      p0[r] = (_Float16)e0; p1[r] = (_Float16)e1;
    }
    pp[0][t] = p0; pp[1][t] = p1;
  }

  // ---- row partial sums -> wsum (no barrier yet) ----
  for (int h = 0; h < 2; ++h) {
    float s = psum[h];
    s += __shfl_xor(s, 16);
    s += __shfl_xor(s, 32);
    if (lg == 0) wsum[w][h * 16 + lr] = s;
  }

  // ---- Phase 2: PV via 16x16x16 MFMA; pp IS the A-frag; V load is one
  //      contiguous 512B wave read per (t,dt). No barrier needed before. ----
  const _Float16* vb = nullptr;
  if constexpr (WS)
    vb = Vt2 + (((size_t)(b * 128 + (key0 >> 4)) * 8) * 64 + lane) * 4;
  for (int dt = 0; dt < 8; ++dt) {
    f32x4 o0 = {0.f, 0.f, 0.f, 0.f}, o1 = {0.f, 0.f, 0.f, 0.f};
#pragma unroll
    for (int t = 0; t < 16; ++t) {
      // B[k=key=16t+4lg+i][n=d=16dt+lr]
      f16x4 bv;
      if constexpr (WS) {
        bv = *(const f16x4*)(vb + (size_t)t * 2048 + dt * 256);
      } else {
        for (int i = 0; i < 4; ++i)
          bv[i] = (_Float16)Vf[((size_t)b * S_ + key0 + 16 * t + 4 * lg + i) * D_ + dt * 16 + lr];
      }
      o0 = __builtin_amdgcn_mfma_f32_16x16x16f16(pp[0][t], bv, o0, 0, 0, 0);
      o1 = __builtin_amdgcn_mfma_f32_16x16x16f16(pp[1][t], bv, o1, 0, 0, 0);
    }
    // D layout: lane holds O[qrow-in-half = 4lg+r][d = 16dt+lr]
    for (int r = 0; r < 4; ++r) {
      opart[w][4 * lg + r][dt * 16 + lr]      = (_Float16)o0[r];
      opart[w][16 + 4 * lg + r][dt * 16 + lr] = (_Float16)o1[r];
    }
  }

  __syncthreads();   // the ONLY barrier

  // ---- Epilogue: all stores fire-and-forget ----
  // row sums from wsum (fixed order, deterministic)
  float s0 = 0.f, s1 = 0.f;
  for (int wv = 0; wv < NW; ++wv) { s0 += wsum[wv][lr]; s1 += wsum[wv][16 + lr]; }
  const float inv0 = 1.0f / s0, inv1 = 1.0f / s1;

  // attn: straight from pp regs; lane's 4 values are CONSECUTIVE keys.
  for (int h = 0; h < 2; ++h) {
    const float inv = h ? inv1 : inv0;
    float* arow = outA + ((size_t)b * S_ + q0 + 16 * h + lr) * S_ + key0 + lg * 4;
#pragma unroll
    for (int t = 0; t < 16; ++t) {
      f16x4 pv = pp[h][t];
      f32x4 av;
      for (int j = 0; j < 4; ++j) av[j] = (float)pv[j] * inv;
      __builtin_nontemporal_store(av, (f32x4*)(arow + 16 * t));
    }
  }

  // O: fixed-order 8-way reduction from LDS, coalesced 32B/thread store.
  {
    const int row = tid >> 4;          // 0..31
    const int dc  = (tid & 15) * 8;    // 0..120
    float racc[8] = {0.f, 0.f, 0.f, 0.f, 0.f, 0.f, 0.f, 0.f};
    for (int wv = 0; wv < NW; ++wv) {
      f16x8 x = *(const f16x8*)&opart[wv][row][dc];
      for (int j = 0; j < 8; ++j) racc[j] += (float)x[j];
    }
    float so = 0.f;
    for (int wv = 0; wv < NW; ++wv) so += wsum[wv][row];
    const float inv = 1.0f / so;
    f32x4 r0, r1;
    for (int j = 0; j < 4; ++j) { r0[j] = racc[j] * inv; r1[j] = racc[4 + j] * inv; }
    float* op = outO + ((size_t)b * S_ + q0 + row) * D_ + dc;
    *(f32x4*)op = r0;
    *(f32x4*)(op + 4) = r1;
  }
}

extern "C" void kernel_launch(void* const* d_in, const int* in_sizes, int n_in,
                              void* d_out, int out_size, void* d_ws, size_t ws_size,
                              hipStream_t stream) {
  const float* Q = (const float*)d_in[0];
  const float* K = (const float*)d_in[1];
  const float* V = (const float*)d_in[2];
  float* outO = (float*)d_out;
  float* outA = outO + NE_;

  const size_t need = 2 * NE_ * sizeof(_Float16);   // 16 MiB (Kh + Vt2)

  const int nblk = B_ * S_ / M_;  // 1024

  if (ws_size >= need) {
    _Float16* Kh  = (_Float16*)d_ws;
    _Float16* Vt2 = Kh + NE_;
    prepass_kernel<<<3072, 256, 0, stream>>>(K, V, Kh, Vt2);
    attn_fused<true><<<nblk, 512, 0, stream>>>(Q, nullptr, nullptr,
                                               Kh, Vt2, outO, outA);
  } else {
    attn_fused<false><<<nblk, 512, 0, stream>>>(Q, K, V,
                                                nullptr, nullptr, outO, outA);
  }
}

// Round 7
// 237.965 us; speedup vs baseline: 1.2900x; 1.2900x over previous
//
#include <hip/hip_runtime.h>
#include <cstdint>
#include <cstddef>

#define B_ 16
#define S_ 2048
#define D_ 128
#define M_ 32            // q-rows per block
#define NW 8             // waves per block
#define KPW 256          // keys per wave
#define OST 136          // opart row stride in halves (16B-aligned rows)

typedef float  f32x4 __attribute__((ext_vector_type(4)));
typedef _Float16 f16x8 __attribute__((ext_vector_type(8)));
typedef _Float16 f16x4 __attribute__((ext_vector_type(4)));

// log2(e) / sqrt(128)
#define SCALE_ 0.12751743f

#define NE_ ((size_t)B_ * S_ * D_)   // 4,194,304 per tensor

// ---------------- pre-pass ----------------
// blocks [0,2048): V -> Vt2, PV-fragment-native tiled layout:
//   Vt2[((b*128 + kt)*8 + dt)*64 + lane][i]  (f16, i=0..3)
//   holds V[b][key = kt*16 + 4*(lane>>4) + i][d = dt*16 + (lane&15)]
//   -> the 16x16x16 PV B-frag load is ONE contiguous 512B wave read.
// blocks [2048,3072): K f32 -> f16 row-major
__global__ void prepass_kernel(const float* __restrict__ K,
                               const float* __restrict__ V,
                               _Float16* __restrict__ Kh,
                               _Float16* __restrict__ Vt2) {
  const int blk = blockIdx.x;
  if (blk < 2048) {
    const int b  = blk >> 7;        // 16 batches
    const int kt = blk & 127;       // 128 key-tiles of 16
    const int tid = threadIdx.x;
    const int lg = tid >> 6;        // 0..3
    const int i  = (tid >> 4) & 3;  // 0..3
    const int lr = tid & 15;        // 0..15
    const size_t vrow = ((size_t)b * S_ + kt * 16 + 4 * lg + i) * D_;
    const size_t obase = (((size_t)(b * 128 + kt) * 8) * 64 + lg * 16 + lr) * 4 + i;
#pragma unroll
    for (int dt = 0; dt < 8; ++dt) {
      float val = V[vrow + dt * 16 + lr];
      Vt2[obase + (size_t)dt * 256] = (_Float16)val;   // dt stride = 64*4 halves
    }
  } else {
    int rel = blk - 2048;      // 0..1023
    const int n4 = (int)(NE_ / 4);
    for (int i = rel * 256 + (int)threadIdx.x; i < n4; i += 1024 * 256) {
      f32x4 v = ((const f32x4*)K)[i];
      f16x4 h;
      for (int j = 0; j < 4; ++j) h[j] = (_Float16)v[j];
      ((f16x4*)Kh)[i] = h;
    }
  }
}

// ---------------- fused attention, P fully in registers ----------------
// QK^T computed SWAPPED: S^T tile = mfma16x16x32(A=K rows, B=Q rows).
// Lane(lr,lg) holds S^T[key=16t+4lg+r][qrow=16h+lr]; after exp+f16-pack,
// pp[h][t] is exactly the A-frag of v_mfma_f32_16x16x16_f16. P never
// touches LDS. ONE barrier total; all global stores after it.
// CRITICAL: every loop touching pp/bq is FULLY unrolled so all array
// indices are compile-time constants (else the arrays land in scratch
// and FETCH_SIZE explodes -- observed rounds 5/6).
template <bool WS>
__global__ __launch_bounds__(512, 2)
void attn_fused(const float* __restrict__ Qf, const float* __restrict__ Kf,
                const float* __restrict__ Vf,
                const _Float16* __restrict__ Kh, const _Float16* __restrict__ Vt2,
                float* __restrict__ outO, float* __restrict__ outA) {
  __shared__ _Float16 opart[NW][M_][OST];   // per-wave O partials (~69.6 KB)
  __shared__ float wsum[NW][M_];

  const int tid  = threadIdx.x;
  const int w    = tid >> 6;
  const int lane = tid & 63;
  const int lg   = lane >> 4;   // 0..3
  const int lr   = lane & 15;   // 0..15
  const int blk  = blockIdx.x;
  const int b    = blk & 15;    // batch -> XCD = b&7 (2 batches per XCD L2)
  const int qt   = blk >> 4;    // 0..63
  const int q0   = qt * M_;
  const int key0 = w * KPW;

  // ---- Q B-frags: B[k=32kk+8lg+j][n=qrow=16h+lr] (load f32, cvt f16) ----
  f16x8 bq[2][4];
#pragma unroll
  for (int h = 0; h < 2; ++h) {
    const float* qp = Qf + ((size_t)b * S_ + q0 + 16 * h + lr) * D_;
#pragma unroll
    for (int kk = 0; kk < 4; ++kk) {
      const float* p = qp + kk * 32 + lg * 8;
      f32x4 v0 = *(const f32x4*)p, v1 = *(const f32x4*)(p + 4);
      f16x8 a;
#pragma unroll
      for (int j = 0; j < 4; ++j) { a[j] = (_Float16)v0[j]; a[4 + j] = (_Float16)v1[j]; }
      bq[h][kk] = a;
    }
  }

  // ---- Phase 1: S^T = K·Q^T, P = exp(S/temper) packed in registers ----
  f16x4 pp[2][16];            // 64 VGPRs: the PV A-fragments
  float psum[2] = {0.f, 0.f};
#pragma unroll
  for (int t = 0; t < 16; ++t) {
    f32x4 acc0 = {0.f, 0.f, 0.f, 0.f}, acc1 = {0.f, 0.f, 0.f, 0.f};
    const size_t krow = (size_t)b * S_ + key0 + 16 * t + lr;
#pragma unroll
    for (int kk = 0; kk < 4; ++kk) {
      // A[m=key row = lr][k = 32kk+8lg+j]
      f16x8 ka;
      if constexpr (WS) {
        ka = *(const f16x8*)(Kh + krow * D_ + kk * 32 + lg * 8);
      } else {
        const float* p = Kf + krow * D_ + kk * 32 + lg * 8;
        f32x4 v0 = *(const f32x4*)p, v1 = *(const f32x4*)(p + 4);
#pragma unroll
        for (int j = 0; j < 4; ++j) { ka[j] = (_Float16)v0[j]; ka[4 + j] = (_Float16)v1[j]; }
      }
      acc0 = __builtin_amdgcn_mfma_f32_16x16x32_f16(ka, bq[0][kk], acc0, 0, 0, 0);
      acc1 = __builtin_amdgcn_mfma_f32_16x16x32_f16(ka, bq[1][kk], acc1, 0, 0, 0);
    }
    f16x4 p0, p1;
#pragma unroll
    for (int r = 0; r < 4; ++r) {
      float e0 = __builtin_amdgcn_exp2f(acc0[r] * SCALE_);
      float e1 = __builtin_amdgcn_exp2f(acc1[r] * SCALE_);
      psum[0] += e0; psum[1] += e1;
      p0[r] = (_Float16)e0; p1[r] = (_Float16)e1;
    }
    pp[0][t] = p0; pp[1][t] = p1;
  }

  // ---- row partial sums -> wsum (no barrier yet) ----
#pragma unroll
  for (int h = 0; h < 2; ++h) {
    float s = psum[h];
    s += __shfl_xor(s, 16);
    s += __shfl_xor(s, 32);
    if (lg == 0) wsum[w][h * 16 + lr] = s;
  }

  // ---- Phase 2: PV via 16x16x16 MFMA; pp IS the A-frag; V load is one
  //      contiguous 512B wave read per (t,dt). No barrier needed before. ----
  const _Float16* vb = nullptr;
  if constexpr (WS)
    vb = Vt2 + (((size_t)(b * 128 + (key0 >> 4)) * 8) * 64 + lane) * 4;
  for (int dt = 0; dt < 8; ++dt) {
    f32x4 o0 = {0.f, 0.f, 0.f, 0.f}, o1 = {0.f, 0.f, 0.f, 0.f};
#pragma unroll
    for (int t = 0; t < 16; ++t) {
      // B[k=key=16t+4lg+i][n=d=16dt+lr]
      f16x4 bv;
      if constexpr (WS) {
        bv = *(const f16x4*)(vb + (size_t)t * 2048 + dt * 256);
      } else {
#pragma unroll
        for (int i = 0; i < 4; ++i)
          bv[i] = (_Float16)Vf[((size_t)b * S_ + key0 + 16 * t + 4 * lg + i) * D_ + dt * 16 + lr];
      }
      o0 = __builtin_amdgcn_mfma_f32_16x16x16f16(pp[0][t], bv, o0, 0, 0, 0);
      o1 = __builtin_amdgcn_mfma_f32_16x16x16f16(pp[1][t], bv, o1, 0, 0, 0);
    }
    // D layout: lane holds O[qrow-in-half = 4lg+r][d = 16dt+lr]
#pragma unroll
    for (int r = 0; r < 4; ++r) {
      opart[w][4 * lg + r][dt * 16 + lr]      = (_Float16)o0[r];
      opart[w][16 + 4 * lg + r][dt * 16 + lr] = (_Float16)o1[r];
    }
  }

  __syncthreads();   // the ONLY barrier

  // ---- Epilogue: all stores fire-and-forget ----
  // row sums from wsum (fixed order, deterministic)
  float s0 = 0.f, s1 = 0.f;
#pragma unroll
  for (int wv = 0; wv < NW; ++wv) { s0 += wsum[wv][lr]; s1 += wsum[wv][16 + lr]; }
  const float inv0 = 1.0f / s0, inv1 = 1.0f / s1;

  // attn: straight from pp regs; lane's 4 values are CONSECUTIVE keys.
#pragma unroll
  for (int h = 0; h < 2; ++h) {
    const float inv = h ? inv1 : inv0;
    float* arow = outA + ((size_t)b * S_ + q0 + 16 * h + lr) * S_ + key0 + lg * 4;
#pragma unroll
    for (int t = 0; t < 16; ++t) {
      f16x4 pv = pp[h][t];
      f32x4 av;
#pragma unroll
      for (int j = 0; j < 4; ++j) av[j] = (float)pv[j] * inv;
      __builtin_nontemporal_store(av, (f32x4*)(arow + 16 * t));
    }
  }

  // O: fixed-order 8-way reduction from LDS, coalesced 32B/thread store.
  {
    const int row = tid >> 4;          // 0..31
    const int dc  = (tid & 15) * 8;    // 0..120
    float racc[8] = {0.f, 0.f, 0.f, 0.f, 0.f, 0.f, 0.f, 0.f};
#pragma unroll
    for (int wv = 0; wv < NW; ++wv) {
      f16x8 x = *(const f16x8*)&opart[wv][row][dc];
#pragma unroll
      for (int j = 0; j < 8; ++j) racc[j] += (float)x[j];
    }
    float so = 0.f;
#pragma unroll
    for (int wv = 0; wv < NW; ++wv) so += wsum[wv][row];
    const float inv = 1.0f / so;
    f32x4 r0, r1;
#pragma unroll
    for (int j = 0; j < 4; ++j) { r0[j] = racc[j] * inv; r1[j] = racc[4 + j] * inv; }
    float* op = outO + ((size_t)b * S_ + q0 + row) * D_ + dc;
    *(f32x4*)op = r0;
    *(f32x4*)(op + 4) = r1;
  }
}

extern "C" void kernel_launch(void* const* d_in, const int* in_sizes, int n_in,
                              void* d_out, int out_size, void* d_ws, size_t ws_size,
                              hipStream_t stream) {
  const float* Q = (const float*)d_in[0];
  const float* K = (const float*)d_in[1];
  const float* V = (const float*)d_in[2];
  float* outO = (float*)d_out;
  float* outA = outO + NE_;

  const size_t need = 2 * NE_ * sizeof(_Float16);   // 16 MiB (Kh + Vt2)

  const int nblk = B_ * S_ / M_;  // 1024

  if (ws_size >= need) {
    _Float16* Kh  = (_Float16*)d_ws;
    _Float16* Vt2 = Kh + NE_;
    prepass_kernel<<<3072, 256, 0, stream>>>(K, V, Kh, Vt2);
    attn_fused<true><<<nblk, 512, 0, stream>>>(Q, nullptr, nullptr,
                                               Kh, Vt2, outO, outA);
  } else {
    attn_fused<false><<<nblk, 512, 0, stream>>>(Q, K, V,
                                                nullptr, nullptr, outO, outA);
  }
}

// Round 8
// 176.236 us; speedup vs baseline: 1.7418x; 1.3503x over previous
//
#include <hip/hip_runtime.h>
#include <cstdint>
#include <cstddef>

#define B_ 16
#define S_ 2048
#define D_ 128
#define M_ 32            // q-rows per block
#define NW 8             // waves per block
#define KPW 256          // keys per wave
#define OST 136          // opart row stride in halves (16B-aligned rows)

typedef float  f32x4 __attribute__((ext_vector_type(4)));
typedef _Float16 f16x8 __attribute__((ext_vector_type(8)));
typedef _Float16 f16x4 __attribute__((ext_vector_type(4)));

// log2(e) / sqrt(128)
#define SCALE_ 0.12751743f

#define NE_ ((size_t)B_ * S_ * D_)   // 4,194,304 per tensor

// ---------------- pre-pass ----------------
// blocks [0,2048): V -> Vt2, PV-fragment-native tiled layout:
//   Vt2[((b*128 + kt)*8 + dt)*64 + lane][i]  (f16, i=0..3)
//   holds V[b][key = kt*16 + 4*(lane>>4) + i][d = dt*16 + (lane&15)]
//   -> the 16x16x16 PV B-frag load is ONE contiguous 512B wave read.
// blocks [2048,3072): K f32 -> f16 row-major
__global__ void prepass_kernel(const float* __restrict__ K,
                               const float* __restrict__ V,
                               _Float16* __restrict__ Kh,
                               _Float16* __restrict__ Vt2) {
  const int blk = blockIdx.x;
  if (blk < 2048) {
    const int b  = blk >> 7;        // 16 batches
    const int kt = blk & 127;       // 128 key-tiles of 16
    const int tid = threadIdx.x;
    const int lg = tid >> 6;        // 0..3
    const int i  = (tid >> 4) & 3;  // 0..3
    const int lr = tid & 15;        // 0..15
    const size_t vrow = ((size_t)b * S_ + kt * 16 + 4 * lg + i) * D_;
    const size_t obase = (((size_t)(b * 128 + kt) * 8) * 64 + lg * 16 + lr) * 4 + i;
#pragma unroll
    for (int dt = 0; dt < 8; ++dt) {
      float val = V[vrow + dt * 16 + lr];
      Vt2[obase + (size_t)dt * 256] = (_Float16)val;   // dt stride = 64*4 halves
    }
  } else {
    int rel = blk - 2048;      // 0..1023
    const int n4 = (int)(NE_ / 4);
    for (int i = rel * 256 + (int)threadIdx.x; i < n4; i += 1024 * 256) {
      f32x4 v = ((const f32x4*)K)[i];
      f16x4 h;
      for (int j = 0; j < 4; ++j) h[j] = (_Float16)v[j];
      ((f16x4*)Kh)[i] = h;
    }
  }
}

// ---------------- fused attention, P fully in registers ----------------
// QK^T computed SWAPPED: S^T tile = mfma16x16x32(A=K rows, B=Q rows).
// Lane(lr,lg) holds S^T[key=16t+4lg+r][qrow=16h+lr]; after exp+f16-pack,
// pp[h][t] is exactly the A-frag of v_mfma_f32_16x16x16_f16. P never
// touches LDS.
// Store discipline (learned R1-R7): attn stores INTERLEAVED with the PV
// MFMA loop (keeps the write pipe busy alongside compute; avoids the
// epilogue store-drain convoy), CACHEABLE (not NT) so L2 merges the
// 64B per-row segments into full 128B lines before writeback.
// All loops touching pp are FULLY unrolled (compile-time indices only;
// runtime-indexed ext_vector arrays go to scratch -- rounds 5/6).
template <bool WS>
__global__ __launch_bounds__(512, 2)
void attn_fused(const float* __restrict__ Qf, const float* __restrict__ Kf,
                const float* __restrict__ Vf,
                const _Float16* __restrict__ Kh, const _Float16* __restrict__ Vt2,
                float* __restrict__ outO, float* __restrict__ outA) {
  __shared__ _Float16 opart[NW][M_][OST];   // per-wave O partials (~69.6 KB)
  __shared__ float wsum[NW][M_];

  const int tid  = threadIdx.x;
  const int w    = tid >> 6;
  const int lane = tid & 63;
  const int lg   = lane >> 4;   // 0..3
  const int lr   = lane & 15;   // 0..15
  const int blk  = blockIdx.x;
  const int b    = blk & 15;    // batch -> XCD = b&7 (2 batches per XCD L2)
  const int qt   = blk >> 4;    // 0..63
  const int q0   = qt * M_;
  const int key0 = w * KPW;

  // ---- Q B-frags: B[k=32kk+8lg+j][n=qrow=16h+lr] (load f32, cvt f16) ----
  f16x8 bq[2][4];
#pragma unroll
  for (int h = 0; h < 2; ++h) {
    const float* qp = Qf + ((size_t)b * S_ + q0 + 16 * h + lr) * D_;
#pragma unroll
    for (int kk = 0; kk < 4; ++kk) {
      const float* p = qp + kk * 32 + lg * 8;
      f32x4 v0 = *(const f32x4*)p, v1 = *(const f32x4*)(p + 4);
      f16x8 a;
#pragma unroll
      for (int j = 0; j < 4; ++j) { a[j] = (_Float16)v0[j]; a[4 + j] = (_Float16)v1[j]; }
      bq[h][kk] = a;
    }
  }

  // ---- Phase 1: S^T = K·Q^T, P = exp(S/temper) packed in registers ----
  f16x4 pp[2][16];            // 64 VGPRs: the PV A-fragments
  float psum[2] = {0.f, 0.f};
#pragma unroll
  for (int t = 0; t < 16; ++t) {
    f32x4 acc0 = {0.f, 0.f, 0.f, 0.f}, acc1 = {0.f, 0.f, 0.f, 0.f};
    const size_t krow = (size_t)b * S_ + key0 + 16 * t + lr;
#pragma unroll
    for (int kk = 0; kk < 4; ++kk) {
      // A[m=key row = lr][k = 32kk+8lg+j]
      f16x8 ka;
      if constexpr (WS) {
        ka = *(const f16x8*)(Kh + krow * D_ + kk * 32 + lg * 8);
      } else {
        const float* p = Kf + krow * D_ + kk * 32 + lg * 8;
        f32x4 v0 = *(const f32x4*)p, v1 = *(const f32x4*)(p + 4);
#pragma unroll
        for (int j = 0; j < 4; ++j) { ka[j] = (_Float16)v0[j]; ka[4 + j] = (_Float16)v1[j]; }
      }
      acc0 = __builtin_amdgcn_mfma_f32_16x16x32_f16(ka, bq[0][kk], acc0, 0, 0, 0);
      acc1 = __builtin_amdgcn_mfma_f32_16x16x32_f16(ka, bq[1][kk], acc1, 0, 0, 0);
    }
    f16x4 p0, p1;
#pragma unroll
    for (int r = 0; r < 4; ++r) {
      float e0 = __builtin_amdgcn_exp2f(acc0[r] * SCALE_);
      float e1 = __builtin_amdgcn_exp2f(acc1[r] * SCALE_);
      psum[0] += e0; psum[1] += e1;
      p0[r] = (_Float16)e0; p1[r] = (_Float16)e1;
    }
    pp[0][t] = p0; pp[1][t] = p1;
  }

  // ---- row partial sums -> wsum ----
#pragma unroll
  for (int h = 0; h < 2; ++h) {
    float s = psum[h];
    s += __shfl_xor(s, 16);
    s += __shfl_xor(s, 32);
    if (lg == 0) wsum[w][h * 16 + lr] = s;
  }

  __syncthreads();   // barrier #1: wsum complete -> inv available

  float s0 = 0.f, s1 = 0.f;
#pragma unroll
  for (int wv = 0; wv < NW; ++wv) { s0 += wsum[wv][lr]; s1 += wsum[wv][16 + lr]; }
  const float inv0 = 1.0f / s0, inv1 = 1.0f / s1;

  // ---- Phase 2: PV via 16x16x16 MFMA with attn stores INTERLEAVED.
  //      pp IS the A-frag; V load is one contiguous 512B wave read per
  //      (t,dt); 4 attn-row stores (cacheable) per dt iteration. ----
  const _Float16* vb = nullptr;
  if constexpr (WS)
    vb = Vt2 + (((size_t)(b * 128 + (key0 >> 4)) * 8) * 64 + lane) * 4;
  float* arow0 = outA + ((size_t)b * S_ + q0 + lr) * S_ + key0 + lg * 4;
  float* arow1 = outA + ((size_t)b * S_ + q0 + 16 + lr) * S_ + key0 + lg * 4;

#pragma unroll
  for (int dt = 0; dt < 8; ++dt) {
    f32x4 o0 = {0.f, 0.f, 0.f, 0.f}, o1 = {0.f, 0.f, 0.f, 0.f};
#pragma unroll
    for (int t = 0; t < 16; ++t) {
      // B[k=key=16t+4lg+i][n=d=16dt+lr]
      f16x4 bv;
      if constexpr (WS) {
        bv = *(const f16x4*)(vb + (size_t)t * 2048 + dt * 256);
      } else {
#pragma unroll
        for (int i = 0; i < 4; ++i)
          bv[i] = (_Float16)Vf[((size_t)b * S_ + key0 + 16 * t + 4 * lg + i) * D_ + dt * 16 + lr];
      }
      o0 = __builtin_amdgcn_mfma_f32_16x16x16f16(pp[0][t], bv, o0, 0, 0, 0);
      o1 = __builtin_amdgcn_mfma_f32_16x16x16f16(pp[1][t], bv, o1, 0, 0, 0);
    }
    // D layout: lane holds O[qrow-in-half = 4lg+r][d = 16dt+lr]
#pragma unroll
    for (int r = 0; r < 4; ++r) {
      opart[w][4 * lg + r][dt * 16 + lr]      = (_Float16)o0[r];
      opart[w][16 + 4 * lg + r][dt * 16 + lr] = (_Float16)o1[r];
    }
    // interleaved attn stores: 2 t-slots per dt (consecutive t -> the two
    // 64B row-segments are adjacent; L2 merges into full lines)
#pragma unroll
    for (int tt = 0; tt < 2; ++tt) {
      const int t = dt * 2 + tt;
      f16x4 pv0 = pp[0][t], pv1 = pp[1][t];
      f32x4 a0, a1;
#pragma unroll
      for (int j = 0; j < 4; ++j) {
        a0[j] = (float)pv0[j] * inv0;
        a1[j] = (float)pv1[j] * inv1;
      }
      *(f32x4*)(arow0 + 16 * t) = a0;
      *(f32x4*)(arow1 + 16 * t) = a1;
    }
  }

  __syncthreads();   // barrier #2: opart complete

  // ---- O epilogue: fixed-order 8-way reduction, 32B/thread store ----
  {
    const int row = tid >> 4;          // 0..31
    const int dc  = (tid & 15) * 8;    // 0..120
    float racc[8] = {0.f, 0.f, 0.f, 0.f, 0.f, 0.f, 0.f, 0.f};
#pragma unroll
    for (int wv = 0; wv < NW; ++wv) {
      f16x8 x = *(const f16x8*)&opart[wv][row][dc];
#pragma unroll
      for (int j = 0; j < 8; ++j) racc[j] += (float)x[j];
    }
    float so = 0.f;
#pragma unroll
    for (int wv = 0; wv < NW; ++wv) so += wsum[wv][row];
    const float inv = 1.0f / so;
    f32x4 r0, r1;
#pragma unroll
    for (int j = 0; j < 4; ++j) { r0[j] = racc[j] * inv; r1[j] = racc[4 + j] * inv; }
    float* op = outO + ((size_t)b * S_ + q0 + row) * D_ + dc;
    *(f32x4*)op = r0;
    *(f32x4*)(op + 4) = r1;
  }
}

extern "C" void kernel_launch(void* const* d_in, const int* in_sizes, int n_in,
                              void* d_out, int out_size, void* d_ws, size_t ws_size,
                              hipStream_t stream) {
  const float* Q = (const float*)d_in[0];
  const float* K = (const float*)d_in[1];
  const float* V = (const float*)d_in[2];
  float* outO = (float*)d_out;
  float* outA = outO + NE_;

  const size_t need = 2 * NE_ * sizeof(_Float16);   // 16 MiB (Kh + Vt2)

  const int nblk = B_ * S_ / M_;  // 1024

  if (ws_size >= need) {
    _Float16* Kh  = (_Float16*)d_ws;
    _Float16* Vt2 = Kh + NE_;
    prepass_kernel<<<3072, 256, 0, stream>>>(K, V, Kh, Vt2);
    attn_fused<true><<<nblk, 512, 0, stream>>>(Q, nullptr, nullptr,
                                               Kh, Vt2, outO, outA);
  } else {
    attn_fused<false><<<nblk, 512, 0, stream>>>(Q, K, V,
                                                nullptr, nullptr, outO, outA);
  }
}